// Round 15
// baseline (249.307 us; speedup 1.0000x reference)
//
#include <hip/hip_runtime.h>
#include <hip/hip_bf16.h>

#define SEQ 2048
#define HID 3584
#define NQH 28
#define NKVH 4
#define HD 128
#define QKVN 4608
#define WIN 1024

typedef __bf16 bf16x8 __attribute__((ext_vector_type(8)));
typedef float f32x4 __attribute__((ext_vector_type(4)));
typedef float f32x16 __attribute__((ext_vector_type(16)));
typedef unsigned int u32x4 __attribute__((ext_vector_type(4)));
typedef unsigned short u16x4 __attribute__((ext_vector_type(4)));

static __device__ __forceinline__ unsigned short f2bf(float f) {
  unsigned int u = __builtin_bit_cast(unsigned int, f);
  u += 0x7fffu + ((u >> 16) & 1u);
  return (unsigned short)(u >> 16);
}
static __device__ __forceinline__ float bf2f(unsigned short h) {
  unsigned int u = ((unsigned int)h) << 16;
  return __builtin_bit_cast(float, u);
}
// packed bf16 convert: D[15:0]=bf16(a), D[31:16]=bf16(b)
static __device__ __forceinline__ unsigned int pkbf(float a, float b) {
  unsigned int r;
  asm("v_cvt_pk_bf16_f32 %0, %1, %2" : "=v"(r) : "v"(a), "v"(b));
  return r;
}

// async global->LDS, 16B per lane. lds base must be wave-uniform; HW adds lane*16.
static __device__ __forceinline__ void gload16(const unsigned short* g, unsigned short* l) {
  __builtin_amdgcn_global_load_lds(
      (const __attribute__((address_space(1))) unsigned int*)g,
      (__attribute__((address_space(3))) unsigned int*)l, 16, 0, 0);
}

// ---------- fused prep: cast hidden->bf16 (blocks 0..3583) + transpose-cast wqkv (3584..7615) ----------
__global__ __launch_bounds__(256) void k_prep(const float* __restrict__ hidden,
                                              unsigned short* __restrict__ hbf,
                                              const float* __restrict__ wqkv,
                                              unsigned short* __restrict__ wqkvT) {
  __shared__ unsigned short tile[64][66];
  const int b = blockIdx.x;
  if (b < 3584) {
    int i = b * 256 + threadIdx.x;  // 917504 total = 3584*256 exactly
    f32x4 a = ((const f32x4*)hidden)[2 * i];
    f32x4 c = ((const f32x4*)hidden)[2 * i + 1];
    union { unsigned short s[8]; u32x4 v; } u;
#pragma unroll
    for (int j = 0; j < 4; j++) { u.s[j] = f2bf(a[j]); u.s[4 + j] = f2bf(c[j]); }
    ((u32x4*)hbf)[i] = u.v;
  } else {
    const int bb = b - 3584;                       // tcast wqkv: R=3584 (56), C=4608 (72)
    const int r0 = (bb % 56) * 64, c0 = (bb / 56) * 64;
    const int t = threadIdx.x;
    const int rg = t >> 4, cg = t & 15;
#pragma unroll
    for (int i = 0; i < 4; i++) {
      int rl = rg + i * 16;
      f32x4 v = *(const f32x4*)(wqkv + (size_t)(r0 + rl) * QKVN + c0 + cg * 4);
#pragma unroll
      for (int j = 0; j < 4; j++) tile[rl][cg * 4 + j] = f2bf(v[j]);
    }
    __syncthreads();
#pragma unroll
    for (int i = 0; i < 4; i++) {
      int cl = rg + i * 16;
      u16x4 o;
#pragma unroll
      for (int j = 0; j < 4; j++) o[j] = tile[cg * 4 + j][cl];
      *(u16x4*)(wqkvT + (size_t)(c0 + cl) * HID + r0 + cg * 4) = o;
    }
  }
}

// ---------- transpose + cast: out[c][r] = bf16(in[r][c]), R,C multiples of 64 ----------
__global__ __launch_bounds__(256) void k_tcast(const float* __restrict__ in,
                                               unsigned short* __restrict__ out, int R, int C) {
  __shared__ unsigned short tile[64][66];
  const int r0 = blockIdx.x * 64, c0 = blockIdx.y * 64;
  const int t = threadIdx.x;
  const int rg = t >> 4, cg = t & 15;
#pragma unroll
  for (int i = 0; i < 4; i++) {
    int rl = rg + i * 16;
    f32x4 v = *(const f32x4*)(in + (size_t)(r0 + rl) * C + c0 + cg * 4);
#pragma unroll
    for (int j = 0; j < 4; j++) tile[rl][cg * 4 + j] = f2bf(v[j]);
  }
  __syncthreads();
#pragma unroll
  for (int i = 0; i < 4; i++) {
    int cl = rg + i * 16;
    u16x4 o;
#pragma unroll
    for (int j = 0; j < 4; j++) o[j] = tile[cg * 4 + j][cl];
    *(u16x4*)(out + (size_t)(c0 + cl) * R + r0 + cg * 4) = o;
  }
}

// ---------- V transpose (bf16): vt[g*128+d][s] = qkv[s][4096 + g*128 + d] ----------
__global__ __launch_bounds__(256) void k_vtrans(const unsigned short* __restrict__ qkv,
                                                unsigned short* __restrict__ vt) {
  __shared__ unsigned short tile[64][66];
  const int r0 = blockIdx.x * 64;  // seq
  const int c0 = blockIdx.y * 64;  // g*128+d in [0,512)
  const int t = threadIdx.x;
  const int rg = t >> 4, cg = t & 15;
#pragma unroll
  for (int i = 0; i < 4; i++) {
    int rl = rg + i * 16;
    u16x4 v = *(const u16x4*)(qkv + (size_t)(r0 + rl) * QKVN + (NQH + NKVH) * HD + c0 + cg * 4);
#pragma unroll
    for (int j = 0; j < 4; j++) tile[rl][cg * 4 + j] = v[j];
  }
  __syncthreads();
#pragma unroll
  for (int i = 0; i < 4; i++) {
    int cl = rg + i * 16;
    u16x4 o;
#pragma unroll
    for (int j = 0; j < 4; j++) o[j] = tile[cg * 4 + j][cl];
    *(u16x4*)(vt + (size_t)(c0 + cl) * SEQ + r0 + cg * 4) = o;
  }
}

// ---------- RoPE in-place on q (heads 0..27) and k (heads 28..31) ----------
__global__ __launch_bounds__(256) void k_rope(unsigned short* __restrict__ qkv,
                                              const float* __restrict__ cosb,
                                              const float* __restrict__ sinb) {
  int idx = blockIdx.x * 256 + threadIdx.x;  // 2048*32*16 total
  int d4 = idx & 15;
  int head = (idx >> 4) & 31;
  int s = idx >> 9;
  unsigned short* row = qkv + (size_t)s * QKVN + head * HD;  // heads 0..31 are contiguous
  int d = d4 * 4;
  u16x4 x1v = *(u16x4*)(row + d);
  u16x4 x2v = *(u16x4*)(row + 64 + d);
  f32x4 c1 = *(const f32x4*)(cosb + s * HD + d);
  f32x4 s1 = *(const f32x4*)(sinb + s * HD + d);
  f32x4 c2 = *(const f32x4*)(cosb + s * HD + 64 + d);
  f32x4 s2 = *(const f32x4*)(sinb + s * HD + 64 + d);
  u16x4 o1, o2;
#pragma unroll
  for (int j = 0; j < 4; j++) {
    float x1 = bf2f(x1v[j]), x2 = bf2f(x2v[j]);
    o1[j] = f2bf(x1 * c1[j] - x2 * s1[j]);
    o2[j] = f2bf(x2 * c2[j] + x1 * s2[j]);
  }
  *(u16x4*)(row + d) = o1;
  *(u16x4*)(row + 64 + d) = o2;
}

// ================= 128 x (64*NB64) 4-wave GEMM, minimum-2-phase, 2 blocks/CU =================
// (structure unchanged from round 12; QKV now also NB64=2 -> 576 blocks, 2.25/CU)
template <int NB64>
__global__ __launch_bounds__(256, 2) void k_gemm128(const unsigned short* __restrict__ A,
                                                    const unsigned short* __restrict__ Bt,
                                                    const float* __restrict__ bias,
                                                    void* __restrict__ Cout,
                                                    int M, int N, int K, int mode) {
  constexpr int BN = 64 * NB64;
  constexpr int FN = BN / 32;    // n-frags per wave (wave covers BN/2)
  __shared__ unsigned short Al[2][128 * 64];
  __shared__ unsigned short Bl[2][BN * 64];

  const int gx = gridDim.x;  // M blocks
  const int nwg = gx * gridDim.y;
  const int lin = blockIdx.y * gx + blockIdx.x;
  const int chunk = nwg >> 3;  // grids are multiples of 8
  const int wg = (lin & 7) * chunk + (lin >> 3);
  const int m0 = (wg % gx) * 128, n0 = (wg / gx) * BN;

  const int t = threadIdx.x;
  const int w = t >> 6, l = t & 63, lg = l >> 4, li = l & 15;
  const int wm = w >> 1, wn = w & 1;  // 2 x 2 waves

  f32x4 acc[4][FN] = {};
  const int nk = K >> 6;

  bf16x8 af[4][2], bfr[FN][2];

  const int slot0 = w * 64 + l;  // 0..255; advance by 256 per staging iter

  auto stA = [&](unsigned short* L, int kt) {
#pragma unroll
    for (int i = 0; i < 4; i++) {
      int s = slot0 + i * 256;
      int row = s >> 3, sl = s & 7;
      int slsrc = sl ^ (row & 7);
      gload16(A + (size_t)(m0 + row) * K + kt * 64 + slsrc * 8, L + (i * 256 + w * 64) * 8);
    }
  };
  auto stB = [&](unsigned short* L, int kt) {
#pragma unroll
    for (int i = 0; i < 2 * NB64; i++) {
      int s = slot0 + i * 256;
      int row = s >> 3, sl = s & 7;
      int slsrc = sl ^ (row & 7);
      gload16(Bt + (size_t)(n0 + row) * K + kt * 64 + slsrc * 8, L + (i * 256 + w * 64) * 8);
    }
  };
  auto rdA = [&](const unsigned short* buf) {
#pragma unroll
    for (int mf = 0; mf < 4; mf++) {
      int row = wm * 64 + mf * 16 + li;
#pragma unroll
      for (int ks = 0; ks < 2; ks++)
        af[mf][ks] = __builtin_bit_cast(
            bf16x8, *(const u32x4*)(buf + row * 64 + ((ks * 32 + lg * 8) ^ ((row & 7) << 3))));
    }
  };
  auto rdB = [&](const unsigned short* buf) {
#pragma unroll
    for (int f = 0; f < FN; f++) {
      int row = wn * (BN / 2) + f * 16 + li;
#pragma unroll
      for (int ks = 0; ks < 2; ks++)
        bfr[f][ks] = __builtin_bit_cast(
            bf16x8, *(const u32x4*)(buf + row * 64 + ((ks * 32 + lg * 8) ^ ((row & 7) << 3))));
    }
  };

  // prologue: stage tile 0, drain, sync
  stA(Al[0], 0);
  stB(Bl[0], 0);
  asm volatile("s_waitcnt vmcnt(0)" ::: "memory");
  __builtin_amdgcn_s_barrier();
  asm volatile("" ::: "memory");

  for (int kt = 0; kt < nk; kt++) {
    const unsigned short* Ab = Al[kt & 1];
    const unsigned short* Bb = Bl[kt & 1];

    // reads first (unpinned), then issue next tile's staging
    rdA(Ab);
    rdB(Bb);
    if (kt + 1 < nk) {
      stA(Al[(kt + 1) & 1], kt + 1);
      stB(Bl[(kt + 1) & 1], kt + 1);
    }

    // MFMA cluster; compiler interleaves counted lgkm waits
    __builtin_amdgcn_s_setprio(1);
#pragma unroll
    for (int mf = 0; mf < 4; mf++)
#pragma unroll
      for (int f = 0; f < FN; f++)
#pragma unroll
        for (int ks = 0; ks < 2; ks++)
          acc[mf][f] = __builtin_amdgcn_mfma_f32_16x16x32_bf16(af[mf][ks], bfr[f][ks],
                                                               acc[mf][f], 0, 0, 0);
    __builtin_amdgcn_s_setprio(0);

    // single drain + single barrier per K-tile (covered by co-resident block)
    asm volatile("s_waitcnt vmcnt(0)" ::: "memory");
    __builtin_amdgcn_s_barrier();
    asm volatile("" ::: "memory");
  }

  if (mode == 0) {
    float bv[FN];
#pragma unroll
    for (int nf = 0; nf < FN; nf++) bv[nf] = bias[n0 + wn * (BN / 2) + nf * 16 + li];
    unsigned short* C16 = (unsigned short*)Cout;
#pragma unroll
    for (int mf = 0; mf < 4; mf++)
#pragma unroll
      for (int nf = 0; nf < FN; nf++)
#pragma unroll
        for (int r = 0; r < 4; r++) {
          int m = m0 + wm * 64 + mf * 16 + lg * 4 + r;
          int n = n0 + wn * (BN / 2) + nf * 16 + li;
          C16[(size_t)m * N + n] = f2bf(acc[mf][nf][r] + bv[nf]);
        }
  } else {
    float* Cf = (float*)Cout;
#pragma unroll
    for (int mf = 0; mf < 4; mf++)
#pragma unroll
      for (int nf = 0; nf < FN; nf++)
#pragma unroll
        for (int r = 0; r < 4; r++) {
          int m = m0 + wm * 64 + mf * 16 + lg * 4 + r;
          int n = n0 + wn * (BN / 2) + nf * 16 + li;
          Cf[(size_t)m * N + n] = acc[mf][nf][r];
        }
  }
}

// ================= flash attention: swapped 32x32, in-reg softmax, LDS-staged K/V =================
// Round-14 version minus the per-tile sched_barrier(0) pins (the barrier +
// "memory"-clobbered waitcnt asm already order all LDS/VMEM ops — same proven
// pattern as the GEMM loop; pins only block profitable compiler overlap).
__global__ __launch_bounds__(256, 2) void k_attn(const unsigned short* __restrict__ qkv,
                                                 const unsigned short* __restrict__ vt,
                                                 unsigned short* __restrict__ attnout) {
  __shared__ unsigned short Kl[2][64 * 128];
  __shared__ unsigned short Vl[2][128 * 64];

  const int head = blockIdx.y;
  const int g = head / 7;
  const int w = threadIdx.x >> 6;
  const int l = threadIdx.x & 63;
  const int c = l & 31;
  const int h = l >> 5;
  const int qb = gridDim.x - 1 - blockIdx.x;  // longest-first
  const int q0 = qb * 128 + w * 32;
  const int qg = q0 + c;

  const float kLog2 = 0.12754137969983664f;  // (1/sqrt(128)) * log2(e)

  const int blo = qb * 128 - 1023;
  const int ktlo = blo > 0 ? blo >> 6 : 0;
  const int kthi = (qb * 128 + 127) >> 6;
  const int wlo = q0 - 1023;
  const int ktlo_w = wlo > 0 ? wlo >> 6 : 0;
  const int kthi_w = (q0 + 31) >> 6;
  const bool wm0 = (q0 - ktlo_w * 64) >= 993;

  bf16x8 qf[8];
  {
    const unsigned short* qp = qkv + (size_t)qg * QKVN + head * HD + h * 8;
#pragma unroll
    for (int dk = 0; dk < 8; dk++)
      qf[dk] = __builtin_bit_cast(bf16x8, *(const u32x4*)(qp + dk * 16));
  }

  f32x16 o0 = {}, o1 = {}, o2 = {}, o3 = {};
  float m = -3e38f, lr = 0.f;

  auto stK4 = [&](unsigned short* L, int kt) {
#pragma unroll
    for (int i = 0; i < 4; i++) {
      int S = w * 64 + l + i * 256;
      int row = S >> 4, sl = S & 15;
      int src = sl ^ (row & 15);
      gload16(qkv + (size_t)(kt * 64 + row) * QKVN + NQH * HD + g * HD + src * 8,
              L + (w * 64 + i * 256) * 8);
    }
  };
  auto stV4 = [&](unsigned short* L, int kt) {
#pragma unroll
    for (int i = 0; i < 4; i++) {
      int S = w * 64 + l + i * 256;
      int row = S >> 3, sl = S & 7;
      int src = sl ^ (row & 7);
      gload16(vt + ((size_t)g * HD + row) * SEQ + kt * 64 + src * 8,
              L + (w * 64 + i * 256) * 8);
    }
  };

  stK4(Kl[0], ktlo);
  stV4(Vl[0], ktlo);

  for (int kt = ktlo; kt <= kthi; kt++) {
    const int buf = (kt - ktlo) & 1;
    const bool st = kt < kthi;
    if (st) { stK4(Kl[buf ^ 1], kt + 1); stV4(Vl[buf ^ 1], kt + 1); }
    if (st) asm volatile("s_waitcnt vmcnt(8)" ::: "memory");
    else    asm volatile("s_waitcnt vmcnt(0)" ::: "memory");
    __builtin_amdgcn_s_barrier();
    asm volatile("" ::: "memory");

    if (kt >= ktlo_w && kt <= kthi_w) {
      const unsigned short* Kb = Kl[buf];
      const unsigned short* Vb = Vl[buf];

      // ---- QK^T (swapped): A = K rows (keys), B = Q ----
      f32x16 s0 = {}, s1 = {};
      __builtin_amdgcn_s_setprio(1);
#pragma unroll
      for (int dk = 0; dk < 8; dk++) {
        int slot = (dk * 2 + h) ^ (c & 15);
        bf16x8 ka = __builtin_bit_cast(bf16x8, *(const u32x4*)(Kb + c * 128 + slot * 8));
        bf16x8 kb2 = __builtin_bit_cast(bf16x8, *(const u32x4*)(Kb + (c + 32) * 128 + slot * 8));
        s0 = __builtin_amdgcn_mfma_f32_32x32x16_bf16(ka, qf[dk], s0, 0, 0, 0);
        s1 = __builtin_amdgcn_mfma_f32_32x32x16_bf16(kb2, qf[dk], s1, 0, 0, 0);
      }
      __builtin_amdgcn_s_setprio(0);

      const bool msk = (kt == kthi_w) || (kt == ktlo_w && wm0);
      if (msk) {
        const int kb0 = kt * 64 + 4 * h;
#pragma unroll
        for (int r = 0; r < 16; r++) {
          int kg = kb0 + (r & 3) + 8 * (r >> 2);
          bool ok0 = (kg <= qg) && (qg - kg < WIN);
          int kg1 = kg + 32;
          bool ok1 = (kg1 <= qg) && (qg - kg1 < WIN);
          s0[r] = ok0 ? s0[r] : -3e38f;
          s1[r] = ok1 ? s1[r] : -3e38f;
        }
      }

      // ---- tree row-max (depth 5) + cross-half ----
      float mx8[8];
#pragma unroll
      for (int i = 0; i < 8; i++)
        mx8[i] = fmaxf(fmaxf(s0[2 * i], s0[2 * i + 1]), fmaxf(s1[2 * i], s1[2 * i + 1]));
      float pmax = fmaxf(fmaxf(fmaxf(mx8[0], mx8[1]), fmaxf(mx8[2], mx8[3])),
                         fmaxf(fmaxf(mx8[4], mx8[5]), fmaxf(mx8[6], mx8[7])));
      pmax = fmaxf(pmax, __shfl_xor(pmax, 32));

      // ---- defer-max (T13) ----
      if (!__all(pmax - m <= 32.0f)) {
        float mn = fmaxf(m, pmax);
        float al = __builtin_amdgcn_exp2f((m - mn) * kLog2);
        o0 *= al; o1 *= al; o2 *= al; o3 *= al;
        lr *= al;
        m = mn;
      }

      // ---- p = exp2((s-m)*k), row sum ----
      float rs = 0.f;
#pragma unroll
      for (int r = 0; r < 16; r++) { s0[r] = __builtin_amdgcn_exp2f((s0[r] - m) * kLog2); rs += s0[r]; }
#pragma unroll
      for (int r = 0; r < 16; r++) { s1[r] = __builtin_amdgcn_exp2f((s1[r] - m) * kLog2); rs += s1[r]; }
      lr += rs + __shfl_xor(rs, 32);

      // ---- pack P -> B-frags: 2 shuffles per kc ----
      u32x4 pf[4];
#pragma unroll
      for (int kc = 0; kc < 4; kc++) {
        const f32x16& sv = (kc < 2) ? s0 : s1;
        const int rb = (kc & 1) * 8;
        unsigned int a0 = pkbf(sv[rb + 0], sv[rb + 1]);
        unsigned int a1 = pkbf(sv[rb + 2], sv[rb + 3]);
        unsigned int b0 = pkbf(sv[rb + 4], sv[rb + 5]);
        unsigned int b1 = pkbf(sv[rb + 6], sv[rb + 7]);
        unsigned int t0 = h ? a0 : b0;   // what my partner needs
        unsigned int t1 = h ? a1 : b1;
        unsigned int x0 = (unsigned int)__shfl_xor((int)t0, 32);
        unsigned int x1 = (unsigned int)__shfl_xor((int)t1, 32);
        u32x4 plo = {a0, a1, x0, x1};    // h=0: own a + partner's a
        u32x4 phi = {x0, x1, b0, b1};    // h=1: partner's b + own b
        pf[kc] = h ? phi : plo;
      }

      // ---- PV (transposed): O^T += V^T . P^T ----
      __builtin_amdgcn_s_setprio(1);
#pragma unroll
      for (int kc = 0; kc < 4; kc++) {
        bf16x8 pfrag = __builtin_bit_cast(bf16x8, pf[kc]);
        int slot = (kc * 2 + h) ^ (c & 7);
        bf16x8 v0 = __builtin_bit_cast(bf16x8, *(const u32x4*)(Vb + (c) * 64 + slot * 8));
        bf16x8 v1 = __builtin_bit_cast(bf16x8, *(const u32x4*)(Vb + (32 + c) * 64 + slot * 8));
        bf16x8 v2 = __builtin_bit_cast(bf16x8, *(const u32x4*)(Vb + (64 + c) * 64 + slot * 8));
        bf16x8 v3 = __builtin_bit_cast(bf16x8, *(const u32x4*)(Vb + (96 + c) * 64 + slot * 8));
        o0 = __builtin_amdgcn_mfma_f32_32x32x16_bf16(v0, pfrag, o0, 0, 0, 0);
        o1 = __builtin_amdgcn_mfma_f32_32x32x16_bf16(v1, pfrag, o1, 0, 0, 0);
        o2 = __builtin_amdgcn_mfma_f32_32x32x16_bf16(v2, pfrag, o2, 0, 0, 0);
        o3 = __builtin_amdgcn_mfma_f32_32x32x16_bf16(v3, pfrag, o3, 0, 0, 0);
      }
      __builtin_amdgcn_s_setprio(0);
    }

    __builtin_amdgcn_s_barrier();
    asm volatile("" ::: "memory");
  }

  const float inv = 1.0f / lr;
  unsigned short* op = attnout + (size_t)qg * HID + head * HD;
#define STOREO(ov, DB)                                                             \
  _Pragma("unroll") for (int qd = 0; qd < 4; qd++) {                               \
    u16x4 tv;                                                                      \
    _Pragma("unroll") for (int j = 0; j < 4; j++) tv[j] = f2bf(ov[qd * 4 + j] * inv); \
    *(u16x4*)(op + (DB) * 32 + qd * 8 + h * 4) = tv;                               \
  }
  STOREO(o0, 0)
  STOREO(o1, 1)
  STOREO(o2, 2)
  STOREO(o3, 3)
#undef STOREO
}

extern "C" void kernel_launch(void* const* d_in, const int* in_sizes, int n_in,
                              void* d_out, int out_size, void* d_ws, size_t ws_size,
                              hipStream_t stream) {
  const float* hidden = (const float*)d_in[0];
  const float* cosb = (const float*)d_in[1];
  const float* sinb = (const float*)d_in[2];
  const float* wqkv = (const float*)d_in[3];
  const float* bqkv = (const float*)d_in[4];
  const float* wo = (const float*)d_in[5];

  char* ws = (char*)d_ws;
  const size_t SZ_HBF = (size_t)SEQ * HID * 2;          // 14,680,064
  const size_t SZ_WQKVT = (size_t)QKVN * HID * 2;       // 33,030,144
  const size_t SZ_QKV = (size_t)SEQ * QKVN * 2;         // 18,874,368
  const size_t SZ_VT = (size_t)NKVH * HD * SEQ * 2;     // 2,097,152
  unsigned short* hbf = (unsigned short*)ws;
  unsigned short* wqkvT = (unsigned short*)(ws + SZ_HBF);
  unsigned short* qkv = (unsigned short*)(ws + SZ_HBF + SZ_WQKVT);
  unsigned short* vt = (unsigned short*)(ws + SZ_HBF + SZ_WQKVT + SZ_QKV);
  unsigned short* attn = (unsigned short*)(ws + SZ_HBF + SZ_WQKVT + SZ_QKV + SZ_VT);
  unsigned short* woT = wqkvT;  // reuse after QKV GEMM consumed wqkvT

  k_prep<<<dim3(3584 + 4032), 256, 0, stream>>>(hidden, hbf, wqkv, wqkvT);
  k_gemm128<2><<<dim3(SEQ / 128, QKVN / 128), 256, 0, stream>>>(hbf, wqkvT, bqkv, qkv, SEQ, QKVN, HID, 0);
  k_rope<<<dim3(SEQ * 32 * 16 / 256), 256, 0, stream>>>(qkv, cosb, sinb);
  k_vtrans<<<dim3(SEQ / 64, (NKVH * HD) / 64), 256, 0, stream>>>(qkv, vt);
  k_tcast<<<dim3(HID / 64, HID / 64), 256, 0, stream>>>(wo, woT, HID, HID);
  k_attn<<<dim3(SEQ / 128, NQH), 256, 0, stream>>>(qkv, vt, attn);
  k_gemm128<2><<<dim3(SEQ / 128, HID / 128), 256, 0, stream>>>(attn, woT, nullptr, d_out, SEQ, HID, HID, 1);
}

// Round 16
// 212.977 us; speedup vs baseline: 1.1706x; 1.1706x over previous
//
#include <hip/hip_runtime.h>
#include <hip/hip_bf16.h>

#define SEQ 2048
#define HID 3584
#define NQH 28
#define NKVH 4
#define HD 128
#define QKVN 4608
#define WIN 1024

typedef __bf16 bf16x8 __attribute__((ext_vector_type(8)));
typedef float f32x4 __attribute__((ext_vector_type(4)));
typedef float f32x16 __attribute__((ext_vector_type(16)));
typedef unsigned int u32x4 __attribute__((ext_vector_type(4)));
typedef unsigned short u16x4 __attribute__((ext_vector_type(4)));

static __device__ __forceinline__ unsigned short f2bf(float f) {
  unsigned int u = __builtin_bit_cast(unsigned int, f);
  u += 0x7fffu + ((u >> 16) & 1u);
  return (unsigned short)(u >> 16);
}
static __device__ __forceinline__ float bf2f(unsigned short h) {
  unsigned int u = ((unsigned int)h) << 16;
  return __builtin_bit_cast(float, u);
}
// packed bf16 convert: D[15:0]=bf16(a), D[31:16]=bf16(b)
static __device__ __forceinline__ unsigned int pkbf(float a, float b) {
  unsigned int r;
  asm("v_cvt_pk_bf16_f32 %0, %1, %2" : "=v"(r) : "v"(a), "v"(b));
  return r;
}

// async global->LDS, 16B per lane. lds base must be wave-uniform; HW adds lane*16.
static __device__ __forceinline__ void gload16(const unsigned short* g, unsigned short* l) {
  __builtin_amdgcn_global_load_lds(
      (const __attribute__((address_space(1))) unsigned int*)g,
      (__attribute__((address_space(3))) unsigned int*)l, 16, 0, 0);
}

// ---------- fused prep: cast hidden->bf16 (blocks 0..3583) + transpose-cast wqkv (3584..7615) ----------
__global__ __launch_bounds__(256) void k_prep(const float* __restrict__ hidden,
                                              unsigned short* __restrict__ hbf,
                                              const float* __restrict__ wqkv,
                                              unsigned short* __restrict__ wqkvT) {
  __shared__ unsigned short tile[64][66];
  const int b = blockIdx.x;
  if (b < 3584) {
    int i = b * 256 + threadIdx.x;  // 917504 total = 3584*256 exactly
    f32x4 a = ((const f32x4*)hidden)[2 * i];
    f32x4 c = ((const f32x4*)hidden)[2 * i + 1];
    union { unsigned short s[8]; u32x4 v; } u;
#pragma unroll
    for (int j = 0; j < 4; j++) { u.s[j] = f2bf(a[j]); u.s[4 + j] = f2bf(c[j]); }
    ((u32x4*)hbf)[i] = u.v;
  } else {
    const int bb = b - 3584;                       // tcast wqkv: R=3584 (56), C=4608 (72)
    const int r0 = (bb % 56) * 64, c0 = (bb / 56) * 64;
    const int t = threadIdx.x;
    const int rg = t >> 4, cg = t & 15;
#pragma unroll
    for (int i = 0; i < 4; i++) {
      int rl = rg + i * 16;
      f32x4 v = *(const f32x4*)(wqkv + (size_t)(r0 + rl) * QKVN + c0 + cg * 4);
#pragma unroll
      for (int j = 0; j < 4; j++) tile[rl][cg * 4 + j] = f2bf(v[j]);
    }
    __syncthreads();
#pragma unroll
    for (int i = 0; i < 4; i++) {
      int cl = rg + i * 16;
      u16x4 o;
#pragma unroll
      for (int j = 0; j < 4; j++) o[j] = tile[cg * 4 + j][cl];
      *(u16x4*)(wqkvT + (size_t)(c0 + cl) * HID + r0 + cg * 4) = o;
    }
  }
}

// ---------- transpose + cast: out[c][r] = bf16(in[r][c]), R,C multiples of 64 ----------
__global__ __launch_bounds__(256) void k_tcast(const float* __restrict__ in,
                                               unsigned short* __restrict__ out, int R, int C) {
  __shared__ unsigned short tile[64][66];
  const int r0 = blockIdx.x * 64, c0 = blockIdx.y * 64;
  const int t = threadIdx.x;
  const int rg = t >> 4, cg = t & 15;
#pragma unroll
  for (int i = 0; i < 4; i++) {
    int rl = rg + i * 16;
    f32x4 v = *(const f32x4*)(in + (size_t)(r0 + rl) * C + c0 + cg * 4);
#pragma unroll
    for (int j = 0; j < 4; j++) tile[rl][cg * 4 + j] = f2bf(v[j]);
  }
  __syncthreads();
#pragma unroll
  for (int i = 0; i < 4; i++) {
    int cl = rg + i * 16;
    u16x4 o;
#pragma unroll
    for (int j = 0; j < 4; j++) o[j] = tile[cg * 4 + j][cl];
    *(u16x4*)(out + (size_t)(c0 + cl) * R + r0 + cg * 4) = o;
  }
}

// ---------- fused RoPE (blocks 0..4095) + V transpose (blocks 4096..4351) ----------
// Independent data: rope touches heads 0..31 (q,k); vtrans reads heads 32..35 (v).
__global__ __launch_bounds__(256) void k_rv(unsigned short* __restrict__ qkv,
                                            const float* __restrict__ cosb,
                                            const float* __restrict__ sinb,
                                            unsigned short* __restrict__ vt) {
  __shared__ unsigned short tile[64][66];
  const int b = blockIdx.x;
  if (b < 4096) {
    int idx = b * 256 + threadIdx.x;  // 2048*32*16 total
    int d4 = idx & 15;
    int head = (idx >> 4) & 31;
    int s = idx >> 9;
    unsigned short* row = qkv + (size_t)s * QKVN + head * HD;
    int d = d4 * 4;
    u16x4 x1v = *(u16x4*)(row + d);
    u16x4 x2v = *(u16x4*)(row + 64 + d);
    f32x4 c1 = *(const f32x4*)(cosb + s * HD + d);
    f32x4 s1 = *(const f32x4*)(sinb + s * HD + d);
    f32x4 c2 = *(const f32x4*)(cosb + s * HD + 64 + d);
    f32x4 s2 = *(const f32x4*)(sinb + s * HD + 64 + d);
    u16x4 o1, o2;
#pragma unroll
    for (int j = 0; j < 4; j++) {
      float x1 = bf2f(x1v[j]), x2 = bf2f(x2v[j]);
      o1[j] = f2bf(x1 * c1[j] - x2 * s1[j]);
      o2[j] = f2bf(x2 * c2[j] + x1 * s2[j]);
    }
    *(u16x4*)(row + d) = o1;
    *(u16x4*)(row + 64 + d) = o2;
  } else {
    const int bb = b - 4096;                    // vtrans: 32 seq-groups x 8 col-groups
    const int r0 = (bb & 31) * 64;              // seq
    const int c0 = (bb >> 5) * 64;              // g*128+d in [0,512)
    const int t = threadIdx.x;
    const int rg = t >> 4, cg = t & 15;
#pragma unroll
    for (int i = 0; i < 4; i++) {
      int rl = rg + i * 16;
      u16x4 v = *(const u16x4*)(qkv + (size_t)(r0 + rl) * QKVN + (NQH + NKVH) * HD + c0 + cg * 4);
#pragma unroll
      for (int j = 0; j < 4; j++) tile[rl][cg * 4 + j] = v[j];
    }
    __syncthreads();
#pragma unroll
    for (int i = 0; i < 4; i++) {
      int cl = rg + i * 16;
      u16x4 o;
#pragma unroll
      for (int j = 0; j < 4; j++) o[j] = tile[cg * 4 + j][cl];
      *(u16x4*)(vt + (size_t)(c0 + cl) * SEQ + r0 + cg * 4) = o;
    }
  }
}

// ================= 128 x (64*NB64) 4-wave GEMM, minimum-2-phase, 2 blocks/CU =================
// QKV: NB64=3 (BN=192, 384 blocks, measured 76us/890TF). O-proj: NB64=2 (448 blocks).
template <int NB64>
__global__ __launch_bounds__(256, 2) void k_gemm128(const unsigned short* __restrict__ A,
                                                    const unsigned short* __restrict__ Bt,
                                                    const float* __restrict__ bias,
                                                    void* __restrict__ Cout,
                                                    int M, int N, int K, int mode) {
  constexpr int BN = 64 * NB64;
  constexpr int FN = BN / 32;    // n-frags per wave (wave covers BN/2)
  __shared__ unsigned short Al[2][128 * 64];
  __shared__ unsigned short Bl[2][BN * 64];

  const int gx = gridDim.x;  // M blocks
  const int nwg = gx * gridDim.y;
  const int lin = blockIdx.y * gx + blockIdx.x;
  const int chunk = nwg >> 3;  // grids are multiples of 8
  const int wg = (lin & 7) * chunk + (lin >> 3);
  const int m0 = (wg % gx) * 128, n0 = (wg / gx) * BN;

  const int t = threadIdx.x;
  const int w = t >> 6, l = t & 63, lg = l >> 4, li = l & 15;
  const int wm = w >> 1, wn = w & 1;  // 2 x 2 waves

  f32x4 acc[4][FN] = {};
  const int nk = K >> 6;

  bf16x8 af[4][2], bfr[FN][2];

  const int slot0 = w * 64 + l;  // 0..255; advance by 256 per staging iter

  auto stA = [&](unsigned short* L, int kt) {
#pragma unroll
    for (int i = 0; i < 4; i++) {
      int s = slot0 + i * 256;
      int row = s >> 3, sl = s & 7;
      int slsrc = sl ^ (row & 7);
      gload16(A + (size_t)(m0 + row) * K + kt * 64 + slsrc * 8, L + (i * 256 + w * 64) * 8);
    }
  };
  auto stB = [&](unsigned short* L, int kt) {
#pragma unroll
    for (int i = 0; i < 2 * NB64; i++) {
      int s = slot0 + i * 256;
      int row = s >> 3, sl = s & 7;
      int slsrc = sl ^ (row & 7);
      gload16(Bt + (size_t)(n0 + row) * K + kt * 64 + slsrc * 8, L + (i * 256 + w * 64) * 8);
    }
  };
  auto rdA = [&](const unsigned short* buf) {
#pragma unroll
    for (int mf = 0; mf < 4; mf++) {
      int row = wm * 64 + mf * 16 + li;
#pragma unroll
      for (int ks = 0; ks < 2; ks++)
        af[mf][ks] = __builtin_bit_cast(
            bf16x8, *(const u32x4*)(buf + row * 64 + ((ks * 32 + lg * 8) ^ ((row & 7) << 3))));
    }
  };
  auto rdB = [&](const unsigned short* buf) {
#pragma unroll
    for (int f = 0; f < FN; f++) {
      int row = wn * (BN / 2) + f * 16 + li;
#pragma unroll
      for (int ks = 0; ks < 2; ks++)
        bfr[f][ks] = __builtin_bit_cast(
            bf16x8, *(const u32x4*)(buf + row * 64 + ((ks * 32 + lg * 8) ^ ((row & 7) << 3))));
    }
  };

  // prologue: stage tile 0, drain, sync
  stA(Al[0], 0);
  stB(Bl[0], 0);
  asm volatile("s_waitcnt vmcnt(0)" ::: "memory");
  __builtin_amdgcn_s_barrier();
  asm volatile("" ::: "memory");

  for (int kt = 0; kt < nk; kt++) {
    const unsigned short* Ab = Al[kt & 1];
    const unsigned short* Bb = Bl[kt & 1];

    // reads first (unpinned), then issue next tile's staging
    rdA(Ab);
    rdB(Bb);
    if (kt + 1 < nk) {
      stA(Al[(kt + 1) & 1], kt + 1);
      stB(Bl[(kt + 1) & 1], kt + 1);
    }

    // MFMA cluster; compiler interleaves counted lgkm waits
    __builtin_amdgcn_s_setprio(1);
#pragma unroll
    for (int mf = 0; mf < 4; mf++)
#pragma unroll
      for (int f = 0; f < FN; f++)
#pragma unroll
        for (int ks = 0; ks < 2; ks++)
          acc[mf][f] = __builtin_amdgcn_mfma_f32_16x16x32_bf16(af[mf][ks], bfr[f][ks],
                                                               acc[mf][f], 0, 0, 0);
    __builtin_amdgcn_s_setprio(0);

    // single drain + single barrier per K-tile (covered by co-resident block)
    asm volatile("s_waitcnt vmcnt(0)" ::: "memory");
    __builtin_amdgcn_s_barrier();
    asm volatile("" ::: "memory");
  }

  if (mode == 0) {
    float bv[FN];
#pragma unroll
    for (int nf = 0; nf < FN; nf++) bv[nf] = bias[n0 + wn * (BN / 2) + nf * 16 + li];
    unsigned short* C16 = (unsigned short*)Cout;
#pragma unroll
    for (int mf = 0; mf < 4; mf++)
#pragma unroll
      for (int nf = 0; nf < FN; nf++)
#pragma unroll
        for (int r = 0; r < 4; r++) {
          int m = m0 + wm * 64 + mf * 16 + lg * 4 + r;
          int n = n0 + wn * (BN / 2) + nf * 16 + li;
          C16[(size_t)m * N + n] = f2bf(acc[mf][nf][r] + bv[nf]);
        }
  } else {
    float* Cf = (float*)Cout;
#pragma unroll
    for (int mf = 0; mf < 4; mf++)
#pragma unroll
      for (int nf = 0; nf < FN; nf++)
#pragma unroll
        for (int r = 0; r < 4; r++) {
          int m = m0 + wm * 64 + mf * 16 + lg * 4 + r;
          int n = n0 + wn * (BN / 2) + nf * 16 + li;
          Cf[(size_t)m * N + n] = acc[mf][nf][r];
        }
  }
}

// ================= flash attention: swapped 32x32, in-reg softmax, LDS-staged K/V =================
// (round-15 version: longest-first dispatch, 8-shuffle P-pack, tree row-max,
//  setprio MFMA clusters, raw exp2, no sched_barrier pins)
__global__ __launch_bounds__(256, 2) void k_attn(const unsigned short* __restrict__ qkv,
                                                 const unsigned short* __restrict__ vt,
                                                 unsigned short* __restrict__ attnout) {
  __shared__ unsigned short Kl[2][64 * 128];
  __shared__ unsigned short Vl[2][128 * 64];

  const int head = blockIdx.y;
  const int g = head / 7;
  const int w = threadIdx.x >> 6;
  const int l = threadIdx.x & 63;
  const int c = l & 31;
  const int h = l >> 5;
  const int qb = gridDim.x - 1 - blockIdx.x;  // longest-first
  const int q0 = qb * 128 + w * 32;
  const int qg = q0 + c;

  const float kLog2 = 0.12754137969983664f;  // (1/sqrt(128)) * log2(e)

  const int blo = qb * 128 - 1023;
  const int ktlo = blo > 0 ? blo >> 6 : 0;
  const int kthi = (qb * 128 + 127) >> 6;
  const int wlo = q0 - 1023;
  const int ktlo_w = wlo > 0 ? wlo >> 6 : 0;
  const int kthi_w = (q0 + 31) >> 6;
  const bool wm0 = (q0 - ktlo_w * 64) >= 993;

  bf16x8 qf[8];
  {
    const unsigned short* qp = qkv + (size_t)qg * QKVN + head * HD + h * 8;
#pragma unroll
    for (int dk = 0; dk < 8; dk++)
      qf[dk] = __builtin_bit_cast(bf16x8, *(const u32x4*)(qp + dk * 16));
  }

  f32x16 o0 = {}, o1 = {}, o2 = {}, o3 = {};
  float m = -3e38f, lr = 0.f;

  auto stK4 = [&](unsigned short* L, int kt) {
#pragma unroll
    for (int i = 0; i < 4; i++) {
      int S = w * 64 + l + i * 256;
      int row = S >> 4, sl = S & 15;
      int src = sl ^ (row & 15);
      gload16(qkv + (size_t)(kt * 64 + row) * QKVN + NQH * HD + g * HD + src * 8,
              L + (w * 64 + i * 256) * 8);
    }
  };
  auto stV4 = [&](unsigned short* L, int kt) {
#pragma unroll
    for (int i = 0; i < 4; i++) {
      int S = w * 64 + l + i * 256;
      int row = S >> 3, sl = S & 7;
      int src = sl ^ (row & 7);
      gload16(vt + ((size_t)g * HD + row) * SEQ + kt * 64 + src * 8,
              L + (w * 64 + i * 256) * 8);
    }
  };

  stK4(Kl[0], ktlo);
  stV4(Vl[0], ktlo);

  for (int kt = ktlo; kt <= kthi; kt++) {
    const int buf = (kt - ktlo) & 1;
    const bool st = kt < kthi;
    if (st) { stK4(Kl[buf ^ 1], kt + 1); stV4(Vl[buf ^ 1], kt + 1); }
    if (st) asm volatile("s_waitcnt vmcnt(8)" ::: "memory");
    else    asm volatile("s_waitcnt vmcnt(0)" ::: "memory");
    __builtin_amdgcn_s_barrier();
    asm volatile("" ::: "memory");

    if (kt >= ktlo_w && kt <= kthi_w) {
      const unsigned short* Kb = Kl[buf];
      const unsigned short* Vb = Vl[buf];

      // ---- QK^T (swapped): A = K rows (keys), B = Q ----
      f32x16 s0 = {}, s1 = {};
      __builtin_amdgcn_s_setprio(1);
#pragma unroll
      for (int dk = 0; dk < 8; dk++) {
        int slot = (dk * 2 + h) ^ (c & 15);
        bf16x8 ka = __builtin_bit_cast(bf16x8, *(const u32x4*)(Kb + c * 128 + slot * 8));
        bf16x8 kb2 = __builtin_bit_cast(bf16x8, *(const u32x4*)(Kb + (c + 32) * 128 + slot * 8));
        s0 = __builtin_amdgcn_mfma_f32_32x32x16_bf16(ka, qf[dk], s0, 0, 0, 0);
        s1 = __builtin_amdgcn_mfma_f32_32x32x16_bf16(kb2, qf[dk], s1, 0, 0, 0);
      }
      __builtin_amdgcn_s_setprio(0);

      const bool msk = (kt == kthi_w) || (kt == ktlo_w && wm0);
      if (msk) {
        const int kb0 = kt * 64 + 4 * h;
#pragma unroll
        for (int r = 0; r < 16; r++) {
          int kg = kb0 + (r & 3) + 8 * (r >> 2);
          bool ok0 = (kg <= qg) && (qg - kg < WIN);
          int kg1 = kg + 32;
          bool ok1 = (kg1 <= qg) && (qg - kg1 < WIN);
          s0[r] = ok0 ? s0[r] : -3e38f;
          s1[r] = ok1 ? s1[r] : -3e38f;
        }
      }

      // ---- tree row-max (depth 5) + cross-half ----
      float mx8[8];
#pragma unroll
      for (int i = 0; i < 8; i++)
        mx8[i] = fmaxf(fmaxf(s0[2 * i], s0[2 * i + 1]), fmaxf(s1[2 * i], s1[2 * i + 1]));
      float pmax = fmaxf(fmaxf(fmaxf(mx8[0], mx8[1]), fmaxf(mx8[2], mx8[3])),
                         fmaxf(fmaxf(mx8[4], mx8[5]), fmaxf(mx8[6], mx8[7])));
      pmax = fmaxf(pmax, __shfl_xor(pmax, 32));

      // ---- defer-max (T13) ----
      if (!__all(pmax - m <= 32.0f)) {
        float mn = fmaxf(m, pmax);
        float al = __builtin_amdgcn_exp2f((m - mn) * kLog2);
        o0 *= al; o1 *= al; o2 *= al; o3 *= al;
        lr *= al;
        m = mn;
      }

      // ---- p = exp2((s-m)*k), row sum ----
      float rs = 0.f;
#pragma unroll
      for (int r = 0; r < 16; r++) { s0[r] = __builtin_amdgcn_exp2f((s0[r] - m) * kLog2); rs += s0[r]; }
#pragma unroll
      for (int r = 0; r < 16; r++) { s1[r] = __builtin_amdgcn_exp2f((s1[r] - m) * kLog2); rs += s1[r]; }
      lr += rs + __shfl_xor(rs, 32);

      // ---- pack P -> B-frags: 2 shuffles per kc ----
      u32x4 pf[4];
#pragma unroll
      for (int kc = 0; kc < 4; kc++) {
        const f32x16& sv = (kc < 2) ? s0 : s1;
        const int rb = (kc & 1) * 8;
        unsigned int a0 = pkbf(sv[rb + 0], sv[rb + 1]);
        unsigned int a1 = pkbf(sv[rb + 2], sv[rb + 3]);
        unsigned int b0 = pkbf(sv[rb + 4], sv[rb + 5]);
        unsigned int b1 = pkbf(sv[rb + 6], sv[rb + 7]);
        unsigned int t0 = h ? a0 : b0;   // what my partner needs
        unsigned int t1 = h ? a1 : b1;
        unsigned int x0 = (unsigned int)__shfl_xor((int)t0, 32);
        unsigned int x1 = (unsigned int)__shfl_xor((int)t1, 32);
        u32x4 plo = {a0, a1, x0, x1};    // h=0: own a + partner's a
        u32x4 phi = {x0, x1, b0, b1};    // h=1: partner's b + own b
        pf[kc] = h ? phi : plo;
      }

      // ---- PV (transposed): O^T += V^T . P^T ----
      __builtin_amdgcn_s_setprio(1);
#pragma unroll
      for (int kc = 0; kc < 4; kc++) {
        bf16x8 pfrag = __builtin_bit_cast(bf16x8, pf[kc]);
        int slot = (kc * 2 + h) ^ (c & 7);
        bf16x8 v0 = __builtin_bit_cast(bf16x8, *(const u32x4*)(Vb + (c) * 64 + slot * 8));
        bf16x8 v1 = __builtin_bit_cast(bf16x8, *(const u32x4*)(Vb + (32 + c) * 64 + slot * 8));
        bf16x8 v2 = __builtin_bit_cast(bf16x8, *(const u32x4*)(Vb + (64 + c) * 64 + slot * 8));
        bf16x8 v3 = __builtin_bit_cast(bf16x8, *(const u32x4*)(Vb + (96 + c) * 64 + slot * 8));
        o0 = __builtin_amdgcn_mfma_f32_32x32x16_bf16(v0, pfrag, o0, 0, 0, 0);
        o1 = __builtin_amdgcn_mfma_f32_32x32x16_bf16(v1, pfrag, o1, 0, 0, 0);
        o2 = __builtin_amdgcn_mfma_f32_32x32x16_bf16(v2, pfrag, o2, 0, 0, 0);
        o3 = __builtin_amdgcn_mfma_f32_32x32x16_bf16(v3, pfrag, o3, 0, 0, 0);
      }
      __builtin_amdgcn_s_setprio(0);
    }

    __builtin_amdgcn_s_barrier();
    asm volatile("" ::: "memory");
  }

  const float inv = 1.0f / lr;
  unsigned short* op = attnout + (size_t)qg * HID + head * HD;
#define STOREO(ov, DB)                                                             \
  _Pragma("unroll") for (int qd = 0; qd < 4; qd++) {                               \
    u16x4 tv;                                                                      \
    _Pragma("unroll") for (int j = 0; j < 4; j++) tv[j] = f2bf(ov[qd * 4 + j] * inv); \
    *(u16x4*)(op + (DB) * 32 + qd * 8 + h * 4) = tv;                               \
  }
  STOREO(o0, 0)
  STOREO(o1, 1)
  STOREO(o2, 2)
  STOREO(o3, 3)
#undef STOREO
}

extern "C" void kernel_launch(void* const* d_in, const int* in_sizes, int n_in,
                              void* d_out, int out_size, void* d_ws, size_t ws_size,
                              hipStream_t stream) {
  const float* hidden = (const float*)d_in[0];
  const float* cosb = (const float*)d_in[1];
  const float* sinb = (const float*)d_in[2];
  const float* wqkv = (const float*)d_in[3];
  const float* bqkv = (const float*)d_in[4];
  const float* wo = (const float*)d_in[5];

  char* ws = (char*)d_ws;
  const size_t SZ_HBF = (size_t)SEQ * HID * 2;          // 14,680,064
  const size_t SZ_WQKVT = (size_t)QKVN * HID * 2;       // 33,030,144
  const size_t SZ_QKV = (size_t)SEQ * QKVN * 2;         // 18,874,368
  const size_t SZ_VT = (size_t)NKVH * HD * SEQ * 2;     // 2,097,152
  unsigned short* hbf = (unsigned short*)ws;
  unsigned short* wqkvT = (unsigned short*)(ws + SZ_HBF);
  unsigned short* qkv = (unsigned short*)(ws + SZ_HBF + SZ_WQKVT);
  unsigned short* vt = (unsigned short*)(ws + SZ_HBF + SZ_WQKVT + SZ_QKV);
  unsigned short* attn = (unsigned short*)(ws + SZ_HBF + SZ_WQKVT + SZ_QKV + SZ_VT);
  unsigned short* woT = wqkvT;  // reuse after QKV GEMM consumed wqkvT

  k_prep<<<dim3(3584 + 4032), 256, 0, stream>>>(hidden, hbf, wqkv, wqkvT);
  k_gemm128<3><<<dim3(SEQ / 128, QKVN / 192), 256, 0, stream>>>(hbf, wqkvT, bqkv, qkv, SEQ, QKVN, HID, 0);
  k_rv<<<dim3(4096 + 256), 256, 0, stream>>>(qkv, cosb, sinb, vt);
  k_tcast<<<dim3(HID / 64, HID / 64), 256, 0, stream>>>(wo, woT, HID, HID);
  k_attn<<<dim3(SEQ / 128, NQH), 256, 0, stream>>>(qkv, vt, attn);
  k_gemm128<2><<<dim3(SEQ / 128, HID / 128), 256, 0, stream>>>(attn, woT, nullptr, d_out, SEQ, HID, HID, 1);
}